// Round 5
// baseline (534.788 us; speedup 1.0000x reference)
//
#include <hip/hip_runtime.h>
#include <math.h>

#define Bq 4
#define Hq 16
#define Nq 4096
#define Dq 64
#define Mq 128
#define Cq 32                          /* chunks per (b,h); L = 128 */
#define Lq 128
#define EPS_PHI 1e-4f
#define EPS_DEN 1e-6f
#define SCALE 0.35355339059327373f     /* 64^-0.25 */
#define INVSQRT_M 0.08838834764831845f /* 1/sqrt(128) */
#define STATE_STRIDE 8320              /* 65*128: [d|z][m] */

#define KSTR 136   /* PK / PKt row stride, bf16 (128+8) */

/* m-axis permutation: perm(m) = (m&15)*8 + (m>>4). Applied to PQ (regs),
   PK (LDS), and WtG's m columns, so all m-contractions are just reordered. */
#define PERM(m) (((m) & 15) * 8 + ((m) >> 4))

typedef __attribute__((ext_vector_type(8))) short bf16x8;
typedef __attribute__((ext_vector_type(4))) short s16x4;
typedef __attribute__((ext_vector_type(4))) float f32x4;

static __device__ inline f32x4 mfma16(bf16x8 a, bf16x8 b, f32x4 c) {
    return __builtin_amdgcn_mfma_f32_16x16x32_bf16(a, b, c, 0, 0, 0);
}

static __device__ inline unsigned short f2bf(float f) {
    unsigned u = __builtin_bit_cast(unsigned, f);
    u += 0x7FFF + ((u >> 16) & 1);          /* RNE */
    return (unsigned short)(u >> 16);
}

static __device__ inline bf16x8 gfrag(const float* p, float scale) {
    float4 a = *(const float4*)p;
    float4 b = *(const float4*)(p + 4);
    union { bf16x8 v; unsigned short s[8]; } u;
    u.s[0] = f2bf(a.x * scale); u.s[1] = f2bf(a.y * scale);
    u.s[2] = f2bf(a.z * scale); u.s[3] = f2bf(a.w * scale);
    u.s[4] = f2bf(b.x * scale); u.s[5] = f2bf(b.y * scale);
    u.s[6] = f2bf(b.z * scale); u.s[7] = f2bf(b.w * scale);
    return u.v;
}

/* K fragment loader that also accumulates sum of squares of scaled values. */
static __device__ inline bf16x8 gfrag_h(const float* p, float* hs) {
    float4 a = *(const float4*)p;
    float4 b = *(const float4*)(p + 4);
    float x0 = a.x * SCALE, x1 = a.y * SCALE, x2 = a.z * SCALE, x3 = a.w * SCALE;
    float x4 = b.x * SCALE, x5 = b.y * SCALE, x6 = b.z * SCALE, x7 = b.w * SCALE;
    *hs += x0 * x0 + x1 * x1 + x2 * x2 + x3 * x3
         + x4 * x4 + x5 * x5 + x6 * x6 + x7 * x7;
    union { bf16x8 v; unsigned short s[8]; } u;
    u.s[0] = f2bf(x0); u.s[1] = f2bf(x1); u.s[2] = f2bf(x2); u.s[3] = f2bf(x3);
    u.s[4] = f2bf(x4); u.s[5] = f2bf(x5); u.s[6] = f2bf(x6); u.s[7] = f2bf(x7);
    return u.v;
}

static __device__ inline bf16x8 ones_frag() {
    union { bf16x8 v; unsigned short s[8]; } u;
    #pragma unroll
    for (int i = 0; i < 8; ++i) u.s[i] = 0x3F80;
    return u.v;
}

// ---------------------------------------------------------------------------
// vconv: per chunk: vT[d][l] bf16 (LDS-staged transpose, coalesced both ways)
// + csumV (f32 column sums, exact eps term).
// ---------------------------------------------------------------------------
__global__ __launch_bounds__(256) void vconv_kernel(
    const float* __restrict__ vin, unsigned short* __restrict__ vT,
    float* __restrict__ csumV) {
    __shared__ __align__(16) unsigned short vt_lds[64 * KSTR];
    __shared__ float csum[4][64];
    const int t = threadIdx.x;
    const int bx = blockIdx.x;
    const int bh = bx >> 5;
    const int l0 = (bx & 31) * Lq;
    const float* vb = vin + ((size_t)bh * Nq + l0) * 64;
    const int d = t & 63, g = t >> 6;

    float s = 0.f;
    #pragma unroll
    for (int rep = 0; rep < 32; ++rep) {
        int l = rep * 4 + g;
        float x = vb[(size_t)l * 64 + d];
        s += x;
        vt_lds[d * KSTR + l] = f2bf(x);
    }
    csum[g][d] = s;
    __syncthreads();
    if (t < 64)
        csumV[(size_t)bx * 64 + t] = csum[0][t] + csum[1][t] + csum[2][t] + csum[3][t];
    unsigned short* vTb = vT + (size_t)bh * 64 * Nq + l0;
    #pragma unroll
    for (int rep = 0; rep < 4; ++rep) {
        int idx = rep * 256 + t;          /* 1024 b128 segments */
        int dd = idx >> 4, seg = idx & 15;
        *(bf16x8*)&vTb[(size_t)dd * Nq + seg * 8] =
            *(const bf16x8*)&vt_lds[dd * KSTR + seg * 8];
    }
}

// ---------------------------------------------------------------------------
__global__ __launch_bounds__(256) void oconv_kernel(
    const float* __restrict__ omega, unsigned short* __restrict__ omb) {
    const int t = threadIdx.x;
    #pragma unroll
    for (int rep = 0; rep < 4; ++rep) {
        int g8 = rep * 256 + t;           /* 1024 groups of 8 */
        const float* p = omega + (size_t)g8 * 8;
        float4 a = *(const float4*)p;
        float4 b = *(const float4*)(p + 4);
        union { bf16x8 v; unsigned short s[8]; } u;
        u.s[0] = f2bf(a.x); u.s[1] = f2bf(a.y); u.s[2] = f2bf(a.z); u.s[3] = f2bf(a.w);
        u.s[4] = f2bf(b.x); u.s[5] = f2bf(b.y); u.s[6] = f2bf(b.z); u.s[7] = f2bf(b.w);
        *(bf16x8*)&omb[(size_t)g8 * 8] = u.v;
    }
}

// ---------------------------------------------------------------------------
// chunkstate: proj_k (h folded into loads, omega bf16 direct), chunk max m_c,
// phi' = exp(proj-h-m_c)/sqrt(M) -> PKt[m][l] (LDS), then swapped MFMA:
// S~^T[d][m] = sum_l vT[d][l] phi'[l][m]  (A from vT global, B from PKt),
// z~[m] via all-ones A-frag. Output STbuf = [d(64)|z][m] f32, coalesced.
// LDS = PKt only (34.8 KB) -> 4 blocks/CU, 8 waves/SIMD.
// ---------------------------------------------------------------------------
__global__ __launch_bounds__(512, 8) void chunkstate_kernel(
    const float* __restrict__ kin, const unsigned short* __restrict__ omb,
    const unsigned short* __restrict__ vT,
    float* __restrict__ partial, float* __restrict__ Sbuf) {
    __shared__ __align__(16) unsigned short PKt[128 * KSTR]; /* [m][l] */
    __shared__ float wred[8];
    const int t = threadIdx.x, w = t >> 6, lane = t & 63;
    const int c16 = lane & 15, qd = lane >> 4;
    const int bx = blockIdx.x;
    const int bh = bx >> 5;
    const int l0 = (bx & 31) * Lq;
    const size_t rowbase = (size_t)bh * Nq + l0;
    const float* kb = kin + rowbase * 64;

    /* ---- proj_k via MFMA, h from the same loads ---- */
    f32x4 acc[8];
    float ssum = 0.f;
    #pragma unroll
    for (int nt = 0; nt < 8; ++nt) acc[nt] = (f32x4){0.f, 0.f, 0.f, 0.f};
    #pragma unroll
    for (int kt = 0; kt < 2; ++kt) {
        bf16x8 a = gfrag_h(kb + (size_t)(16 * w + c16) * 64 + kt * 32 + qd * 8, &ssum);
        #pragma unroll
        for (int nt = 0; nt < 8; ++nt) {
            bf16x8 b = *(const bf16x8*)&omb[(size_t)(16 * nt + c16) * 64 + kt * 32 + qd * 8];
            acc[nt] = mfma16(a, b, acc[nt]);
        }
    }
    ssum += __shfl_xor(ssum, 16);
    ssum += __shfl_xor(ssum, 32);
    const float h_red = 0.5f * ssum;
    const int row0 = 16 * w + 4 * qd;
    float h4[4];
    #pragma unroll
    for (int r = 0; r < 4; ++r) h4[r] = __shfl(h_red, 4 * qd + r);

    /* ---- chunk max ---- */
    float lmax = -1e30f;
    #pragma unroll
    for (int r = 0; r < 4; ++r) {
        #pragma unroll
        for (int nt = 0; nt < 8; ++nt) lmax = fmaxf(lmax, acc[nt][r] - h4[r]);
    }
    #pragma unroll
    for (int o = 1; o <= 32; o <<= 1) lmax = fmaxf(lmax, __shfl_xor(lmax, o));
    if (lane == 0) wred[w] = lmax;
    __syncthreads();                               /* barrier 1: wred */
    float mc = wred[0];
    #pragma unroll
    for (int i = 1; i < 8; ++i) mc = fmaxf(mc, wred[i]);
    if (t == 0) partial[bx] = mc;

    /* ---- phi'_k -> PKt[m][l], packed b64 ---- */
    #pragma unroll
    for (int nt = 0; nt < 8; ++nt) {
        union { s16x4 v; unsigned short s[4]; } u;
        #pragma unroll
        for (int r = 0; r < 4; ++r) {
            float pk = __expf(acc[nt][r] - h4[r] - mc) * INVSQRT_M;
            u.s[r] = f2bf(pk);
        }
        *(s16x4*)&PKt[(16 * nt + c16) * KSTR + row0] = u.v;
    }
    __syncthreads();                               /* barrier 2: PKt ready */

    /* ---- S~^T = vT . PK' (wave w owns m-tile w; 4 d-tiles + z) ---- */
    const unsigned short* vTb = vT + (size_t)bh * 64 * Nq + l0;
    f32x4 accS[4], accz;
    #pragma unroll
    for (int dt = 0; dt < 4; ++dt) accS[dt] = (f32x4){0.f, 0.f, 0.f, 0.f};
    accz = (f32x4){0.f, 0.f, 0.f, 0.f};
    const bf16x8 ones = ones_frag();
    #pragma unroll
    for (int kt = 0; kt < 4; ++kt) {
        bf16x8 bfr = *(const bf16x8*)&PKt[(16 * w + c16) * KSTR + kt * 32 + qd * 8];
        #pragma unroll
        for (int dt = 0; dt < 4; ++dt) {
            bf16x8 afr = *(const bf16x8*)&vTb[(size_t)(16 * dt + c16) * Nq + kt * 32 + qd * 8];
            accS[dt] = mfma16(afr, bfr, accS[dt]);
        }
        accz = mfma16(ones, bfr, accz);
    }
    float* sb = Sbuf + (size_t)bx * STATE_STRIDE;
    #pragma unroll
    for (int dt = 0; dt < 4; ++dt) {
        #pragma unroll
        for (int r = 0; r < 4; ++r)
            sb[(16 * dt + 4 * qd + r) * 128 + 16 * w + c16] = accS[dt][r];
    }
    if (qd == 0) sb[64 * 128 + 16 * w + c16] = accz[0];
}

// ---------------------------------------------------------------------------
__global__ void gmax_kernel(const float* __restrict__ partial, int n, float* __restrict__ gmax) {
    float m = -1e30f;
    for (int i = threadIdx.x; i < n; i += 256) m = fmaxf(m, partial[i]);
    #pragma unroll
    for (int o = 1; o <= 32; o <<= 1) m = fmaxf(m, __shfl_xor(m, o));
    __shared__ float w[4];
    if ((threadIdx.x & 63) == 0) w[threadIdx.x >> 6] = m;
    __syncthreads();
    if (threadIdx.x == 0) gmax[0] = fmaxf(fmaxf(w[0], w[1]), fmaxf(w[2], w[3]));
}

// ---------------------------------------------------------------------------
// prefix: exclusive scan of  e^{m_c-gmax} S~^T + eps-terms over chunks,
// written as bf16 WtG[c][dz][perm(m)] — exactly replay's GEMM2 B layout.
// Reads coalesced ([d][m] row-major), in-register scan (ILP).
// ---------------------------------------------------------------------------
#define PBLK 33   /* ceil(8320/256) slices per (b,h) */
__global__ __launch_bounds__(256) void prefix_kernel(
    const float* __restrict__ Sbuf, unsigned short* __restrict__ WtG,
    const float* __restrict__ csumV,
    const float* __restrict__ partial, const float* __restrict__ gmaxp) {
    const int bh = blockIdx.x / PBLK;
    const int e = (blockIdx.x % PBLK) * 256 + threadIdx.x;
    if (e >= STATE_STRIDE) return;
    const float gm = gmaxp[0];
    const int dz = e >> 7, m = e & 127;
    const int wcol = dz * 128 + PERM(m);
    const size_t base = (size_t)bh * Cq * STATE_STRIDE + e;

    float vals[Cq];
    #pragma unroll
    for (int c = 0; c < Cq; ++c) vals[c] = Sbuf[base + (size_t)c * STATE_STRIDE];

    float running = 0.f;
    #pragma unroll
    for (int c = 0; c < Cq; ++c) {
        const int cx = bh * Cq + c;
        float sc = __expf(partial[cx] - gm);
        float ep = (dz == 64) ? (EPS_PHI * 128.0f)
                              : (EPS_PHI * csumV[(size_t)cx * 64 + dz]);
        WtG[(size_t)cx * STATE_STRIDE + wcol] = f2bf(running);
        running += sc * vals[c] + ep;
    }
}

// ---------------------------------------------------------------------------
// replay: proj (omega bf16 direct, h in-register), phi_q/PQ in registers,
// phi_k -> PK (LDS, the only LDS array: 34.8 KB -> 4 blocks/CU),
// GEMM1 swapped (A_s^T = PK.PQ^T) kept in registers,
// GEMM2 B-frags direct from global: vT (V part), WtG (S_in/z, perm'd),
// const-ones (den V-part). den row broadcast -> every lane owns den.
// ---------------------------------------------------------------------------
__global__ __launch_bounds__(512, 8) void replay_kernel(
    const float* __restrict__ q, const float* __restrict__ kin,
    const unsigned short* __restrict__ omb, const unsigned short* __restrict__ vT,
    const unsigned short* __restrict__ WtG,
    const float* __restrict__ gmaxp, float* __restrict__ out) {
    __shared__ __align__(16) unsigned short PK[128 * KSTR];  /* [l][perm(m)] */
    const int t = threadIdx.x, w = t >> 6, lane = t & 63;
    const int c16 = lane & 15, qd = lane >> 4;
    const int bx = blockIdx.x;
    const int bh = bx >> 5;
    const int l0 = (bx & 31) * Lq;
    const size_t rowbase = (size_t)bh * Nq + l0;
    const float* qb = q + rowbase * 64;
    const float* kb = kin + rowbase * 64;
    const float gmax = gmaxp[0];
    const int row0 = 16 * w + 4 * qd;
    const int arow = 16 * w + c16;

    /* ---- proj_q + proj_k fused; h from the k loads ---- */
    f32x4 accq[8], acck[8];
    float ssum = 0.f;
    #pragma unroll
    for (int nt = 0; nt < 8; ++nt) {
        accq[nt] = (f32x4){0.f, 0.f, 0.f, 0.f};
        acck[nt] = (f32x4){0.f, 0.f, 0.f, 0.f};
    }
    #pragma unroll
    for (int kt = 0; kt < 2; ++kt) {
        bf16x8 aq = gfrag(qb + (size_t)arow * 64 + kt * 32 + qd * 8, SCALE);
        bf16x8 ak = gfrag_h(kb + (size_t)arow * 64 + kt * 32 + qd * 8, &ssum);
        #pragma unroll
        for (int nt = 0; nt < 8; ++nt) {
            bf16x8 b = *(const bf16x8*)&omb[(size_t)(16 * nt + c16) * 64 + kt * 32 + qd * 8];
            accq[nt] = mfma16(aq, b, accq[nt]);
            acck[nt] = mfma16(ak, b, acck[nt]);
        }
    }
    ssum += __shfl_xor(ssum, 16);
    ssum += __shfl_xor(ssum, 32);
    const float h_red = 0.5f * ssum;

    /* ---- phi_q into registers (perm-packed pairs) ---- */
    unsigned pqu[4][4];
    #pragma unroll
    for (int r = 0; r < 4; ++r) {
        float mx = accq[0][r];
        #pragma unroll
        for (int nt = 1; nt < 8; ++nt) mx = fmaxf(mx, accq[nt][r]);
        mx = fmaxf(mx, __shfl_xor(mx, 1));
        mx = fmaxf(mx, __shfl_xor(mx, 2));
        mx = fmaxf(mx, __shfl_xor(mx, 4));
        mx = fmaxf(mx, __shfl_xor(mx, 8));
        #pragma unroll
        for (int i = 0; i < 4; ++i) {
            float lo = __expf(accq[2 * i][r]     - mx) * INVSQRT_M + EPS_PHI;
            float hi = __expf(accq[2 * i + 1][r] - mx) * INVSQRT_M + EPS_PHI;
            pqu[r][i] = (unsigned)f2bf(lo) | ((unsigned)f2bf(hi) << 16);
        }
    }
    /* ---- build bq[kt] (PQ A/B-frag for row arow) via shuffles ---- */
    bf16x8 bq[4];
    {
        const int rsel = c16 & 3;
        #pragma unroll
        for (int kt = 0; kt < 4; ++kt) {
            const int src = 4 * kt + qd + ((c16 >> 2) << 4);
            union { bf16x8 v; unsigned u[4]; } tt;
            #pragma unroll
            for (int i = 0; i < 4; ++i) {
                unsigned v0 = __shfl(pqu[0][i], src);
                unsigned v1 = __shfl(pqu[1][i], src);
                unsigned v2 = __shfl(pqu[2][i], src);
                unsigned v3 = __shfl(pqu[3][i], src);
                unsigned s01 = (rsel & 1) ? v1 : v0;
                unsigned s23 = (rsel & 1) ? v3 : v2;
                tt.u[i] = (rsel & 2) ? s23 : s01;
            }
            bq[kt] = tt.v;
        }
    }
    /* ---- phi_k -> PK[l][perm(m)], b128 packed ---- */
    #pragma unroll
    for (int r = 0; r < 4; ++r) {
        float h = __shfl(h_red, 4 * qd + r);
        union { bf16x8 v; unsigned short s[8]; } u;
        #pragma unroll
        for (int nt = 0; nt < 8; ++nt)
            u.s[nt] = f2bf(__expf(acck[nt][r] - h - gmax) * INVSQRT_M + EPS_PHI);
        *(bf16x8*)&PK[(row0 + r) * KSTR + c16 * 8] = u.v;
    }
    __syncthreads();   /* the ONE barrier: PK visibility */

    /* ---- GEMM1 swapped: a1[lt] = D[l][q-tile] ---- */
    f32x4 a1[8];
    #pragma unroll
    for (int lt = 0; lt < 8; ++lt) {
        a1[lt] = (f32x4){0.f, 0.f, 0.f, 0.f};
        #pragma unroll
        for (int kt = 0; kt < 4; ++kt) {
            bf16x8 a = *(const bf16x8*)&PK[(16 * lt + c16) * KSTR + kt * 32 + qd * 8];
            a1[lt] = mfma16(a, bq[kt], a1[lt]);
        }
    }
    /* ---- causal mask + pack A_s to registers ---- */
    unsigned asu[8][2];
    #pragma unroll
    for (int lt = 0; lt < 8; ++lt) {
        const int lbase = 16 * lt + 4 * qd;
        float m0 = (lbase + 0 <= arow) ? a1[lt][0] : 0.f;
        float m1 = (lbase + 1 <= arow) ? a1[lt][1] : 0.f;
        float m2 = (lbase + 2 <= arow) ? a1[lt][2] : 0.f;
        float m3 = (lbase + 3 <= arow) ? a1[lt][3] : 0.f;
        asu[lt][0] = (unsigned)f2bf(m0) | ((unsigned)f2bf(m1) << 16);
        asu[lt][1] = (unsigned)f2bf(m2) | ((unsigned)f2bf(m3) << 16);
    }
    /* ---- GEMM2: [num|den] = [A_s|PQ] . W ---- */
    const unsigned short* vTb = vT + (size_t)bh * 64 * Nq + l0;
    const unsigned short* wg  = WtG + (size_t)bx * STATE_STRIDE;
    const bf16x8 ones = ones_frag();
    f32x4 acc2[5];
    #pragma unroll
    for (int nt = 0; nt < 5; ++nt) acc2[nt] = (f32x4){0.f, 0.f, 0.f, 0.f};
    {
        const int src0 = c16 + ((2 * qd) & 3) * 16;
        const int src1 = c16 + ((2 * qd + 1) & 3) * 16;
        const int hsel = qd >> 1;
        #pragma unroll
        for (int kt = 0; kt < 4; ++kt) {   /* k = l (V half) */
            union { bf16x8 v; unsigned u[4]; } af;
            unsigned a00 = __shfl(asu[2 * kt][0], src0), a10 = __shfl(asu[2 * kt + 1][0], src0);
            unsigned a01 = __shfl(asu[2 * kt][1], src0), a11 = __shfl(asu[2 * kt + 1][1], src0);
            af.u[0] = hsel ? a10 : a00;
            af.u[1] = hsel ? a11 : a01;
            unsigned b00 = __shfl(asu[2 * kt][0], src1), b10 = __shfl(asu[2 * kt + 1][0], src1);
            unsigned b01 = __shfl(asu[2 * kt][1], src1), b11 = __shfl(asu[2 * kt + 1][1], src1);
            af.u[2] = hsel ? b10 : b00;
            af.u[3] = hsel ? b11 : b01;
            #pragma unroll
            for (int nt = 0; nt < 4; ++nt) {
                bf16x8 b = *(const bf16x8*)&vTb[(size_t)(16 * nt + c16) * Nq + kt * 32 + qd * 8];
                acc2[nt] = mfma16(af.v, b, acc2[nt]);
            }
            acc2[4] = mfma16(af.v, ones, acc2[4]);       /* den V-part */
        }
        #pragma unroll
        for (int kt = 0; kt < 4; ++kt) {   /* k = perm(m) (S_in half) */
            #pragma unroll
            for (int nt = 0; nt < 4; ++nt) {
                bf16x8 b = *(const bf16x8*)&wg[(16 * nt + c16) * 128 + kt * 32 + qd * 8];
                acc2[nt] = mfma16(bq[kt], b, acc2[nt]);
            }
            /* den z-part: broadcast row 64 to all cols -> every lane owns den */
            bf16x8 bz = *(const bf16x8*)&wg[64 * 128 + kt * 32 + qd * 8];
            acc2[4] = mfma16(bq[kt], bz, acc2[4]);
        }
    }
    /* ---- epilogue: den is lane-local now ---- */
    #pragma unroll
    for (int r = 0; r < 4; ++r) {
        float den = acc2[4][r] + EPS_DEN;
        float rd = 1.0f / den;
        #pragma unroll
        for (int nt = 0; nt < 4; ++nt)
            out[(rowbase + row0 + r) * 64 + 16 * nt + c16] = acc2[nt][r] * rd;
    }
}

// ---------------------------------------------------------------------------
extern "C" void kernel_launch(void* const* d_in, const int* in_sizes, int n_in,
                              void* d_out, int out_size, void* d_ws, size_t ws_size,
                              hipStream_t stream) {
    const float* q     = (const float*)d_in[0];
    const float* k     = (const float*)d_in[1];
    const float* v     = (const float*)d_in[2];
    const float* omega = (const float*)d_in[3];
    float* out = (float*)d_out;
    float* ws  = (float*)d_ws;

    const int nChunks = Bq * Hq * Cq;            /* 2048 */
    float* partial = ws;                                       /* 2048 */
    float* gmax    = partial + nChunks;                        /* 16 */
    float* csumV   = gmax + 16;                                /* 2048*64 */
    unsigned short* omb = (unsigned short*)(csumV + (size_t)nChunks * 64);      /* 8192 h */
    unsigned short* vT  = omb + 8192;                          /* 64*64*4096 h = 32 MB */
    unsigned short* WtG = vT + (size_t)64 * 64 * Nq;           /* 2048*8320 h = 34 MB */
    float* Sbuf = (float*)(WtG + (size_t)nChunks * STATE_STRIDE);  /* 68 MB f32 */

    vconv_kernel<<<nChunks, 256, 0, stream>>>(v, vT, csumV);
    oconv_kernel<<<1, 256, 0, stream>>>(omega, omb);
    chunkstate_kernel<<<nChunks, 512, 0, stream>>>(k, omb, vT, partial, Sbuf);
    gmax_kernel<<<1, 256, 0, stream>>>(partial, nChunks, gmax);
    prefix_kernel<<<64 * PBLK, 256, 0, stream>>>(Sbuf, WtG, csumV, partial, gmax);
    replay_kernel<<<nChunks, 512, 0, stream>>>(q, k, omb, vT, WtG, gmax, out);
}

// Round 6
// 416.617 us; speedup vs baseline: 1.2836x; 1.2836x over previous
//
#include <hip/hip_runtime.h>
#include <math.h>

#define Bq 4
#define Hq 16
#define Nq 4096
#define Dq 64
#define Mq 128
#define Cq 32                          /* chunks per (b,h); L = 128 */
#define Lq 128
#define EPS_PHI 1e-4f
#define EPS_DEN 1e-6f
#define SCALE 0.35355339059327373f     /* 64^-0.25 */
#define INVSQRT_M 0.08838834764831845f /* 1/sqrt(128) */
#define STATE_STRIDE 8320              /* 65*128: [d|z][m] */

#define KSTR 136   /* PK / PKt row stride, bf16 (128+8) */

/* m-axis permutation: perm(m) = (m&15)*8 + (m>>4). Applied to PQ (regs),
   PK (LDS), and WtG's m columns, so all m-contractions are just reordered. */
#define PERM(m) (((m) & 15) * 8 + ((m) >> 4))

typedef __attribute__((ext_vector_type(8))) short bf16x8;
typedef __attribute__((ext_vector_type(4))) short s16x4;
typedef __attribute__((ext_vector_type(4))) float f32x4;

static __device__ inline f32x4 mfma16(bf16x8 a, bf16x8 b, f32x4 c) {
    return __builtin_amdgcn_mfma_f32_16x16x32_bf16(a, b, c, 0, 0, 0);
}

static __device__ inline unsigned short f2bf(float f) {
    unsigned u = __builtin_bit_cast(unsigned, f);
    u += 0x7FFF + ((u >> 16) & 1);          /* RNE */
    return (unsigned short)(u >> 16);
}

static __device__ inline bf16x8 gfrag(const float* p, float scale) {
    float4 a = *(const float4*)p;
    float4 b = *(const float4*)(p + 4);
    union { bf16x8 v; unsigned short s[8]; } u;
    u.s[0] = f2bf(a.x * scale); u.s[1] = f2bf(a.y * scale);
    u.s[2] = f2bf(a.z * scale); u.s[3] = f2bf(a.w * scale);
    u.s[4] = f2bf(b.x * scale); u.s[5] = f2bf(b.y * scale);
    u.s[6] = f2bf(b.z * scale); u.s[7] = f2bf(b.w * scale);
    return u.v;
}

/* K fragment loader that also accumulates sum of squares of scaled values. */
static __device__ inline bf16x8 gfrag_h(const float* p, float* hs) {
    float4 a = *(const float4*)p;
    float4 b = *(const float4*)(p + 4);
    float x0 = a.x * SCALE, x1 = a.y * SCALE, x2 = a.z * SCALE, x3 = a.w * SCALE;
    float x4 = b.x * SCALE, x5 = b.y * SCALE, x6 = b.z * SCALE, x7 = b.w * SCALE;
    *hs += x0 * x0 + x1 * x1 + x2 * x2 + x3 * x3
         + x4 * x4 + x5 * x5 + x6 * x6 + x7 * x7;
    union { bf16x8 v; unsigned short s[8]; } u;
    u.s[0] = f2bf(x0); u.s[1] = f2bf(x1); u.s[2] = f2bf(x2); u.s[3] = f2bf(x3);
    u.s[4] = f2bf(x4); u.s[5] = f2bf(x5); u.s[6] = f2bf(x6); u.s[7] = f2bf(x7);
    return u.v;
}

static __device__ inline bf16x8 ones_frag() {
    union { bf16x8 v; unsigned short s[8]; } u;
    #pragma unroll
    for (int i = 0; i < 8; ++i) u.s[i] = 0x3F80;
    return u.v;
}

// ---------------------------------------------------------------------------
// vconv: per chunk: vT[d][l] bf16 (LDS-staged transpose, coalesced both ways)
// + csumV (f32 column sums, exact eps term).
// ---------------------------------------------------------------------------
__global__ __launch_bounds__(256) void vconv_kernel(
    const float* __restrict__ vin, unsigned short* __restrict__ vT,
    float* __restrict__ csumV) {
    __shared__ __align__(16) unsigned short vt_lds[64 * KSTR];
    __shared__ float csum[4][64];
    const int t = threadIdx.x;
    const int bx = blockIdx.x;
    const int bh = bx >> 5;
    const int l0 = (bx & 31) * Lq;
    const float* vb = vin + ((size_t)bh * Nq + l0) * 64;
    const int d = t & 63, g = t >> 6;

    float s = 0.f;
    #pragma unroll
    for (int rep = 0; rep < 32; ++rep) {
        int l = rep * 4 + g;
        float x = vb[(size_t)l * 64 + d];
        s += x;
        vt_lds[d * KSTR + l] = f2bf(x);
    }
    csum[g][d] = s;
    __syncthreads();
    if (t < 64)
        csumV[(size_t)bx * 64 + t] = csum[0][t] + csum[1][t] + csum[2][t] + csum[3][t];
    unsigned short* vTb = vT + (size_t)bh * 64 * Nq + l0;
    #pragma unroll
    for (int rep = 0; rep < 4; ++rep) {
        int idx = rep * 256 + t;          /* 1024 b128 segments */
        int dd = idx >> 4, seg = idx & 15;
        *(bf16x8*)&vTb[(size_t)dd * Nq + seg * 8] =
            *(const bf16x8*)&vt_lds[dd * KSTR + seg * 8];
    }
}

// ---------------------------------------------------------------------------
__global__ __launch_bounds__(256) void oconv_kernel(
    const float* __restrict__ omega, unsigned short* __restrict__ omb) {
    const int t = threadIdx.x;
    #pragma unroll
    for (int rep = 0; rep < 4; ++rep) {
        int g8 = rep * 256 + t;           /* 1024 groups of 8 */
        const float* p = omega + (size_t)g8 * 8;
        float4 a = *(const float4*)p;
        float4 b = *(const float4*)(p + 4);
        union { bf16x8 v; unsigned short s[8]; } u;
        u.s[0] = f2bf(a.x); u.s[1] = f2bf(a.y); u.s[2] = f2bf(a.z); u.s[3] = f2bf(a.w);
        u.s[4] = f2bf(b.x); u.s[5] = f2bf(b.y); u.s[6] = f2bf(b.z); u.s[7] = f2bf(b.w);
        *(bf16x8*)&omb[(size_t)g8 * 8] = u.v;
    }
}

// ---------------------------------------------------------------------------
// chunkstate: proj_k (h folded into loads, omega bf16 direct), chunk max m_c,
// phi' = exp(proj-h-m_c)/sqrt(M) -> PKt[m][l] (LDS), then swapped MFMA:
// S~^T[d][m] = sum_l vT[d][l] phi'[l][m]  (A from vT global, B from PKt),
// z~[m] via all-ones A-frag. Output STbuf = [d(64)|z][m] f32, coalesced.
// launch_bounds (512,4): 128-VGPR budget — occupancy from ACTUAL usage,
// never from forced spills (R5 lesson: (512,8) => 370 MB scratch traffic).
// ---------------------------------------------------------------------------
__global__ __launch_bounds__(512, 4) void chunkstate_kernel(
    const float* __restrict__ kin, const unsigned short* __restrict__ omb,
    const unsigned short* __restrict__ vT,
    float* __restrict__ partial, float* __restrict__ Sbuf) {
    __shared__ __align__(16) unsigned short PKt[128 * KSTR]; /* [m][l] */
    __shared__ float wred[8];
    const int t = threadIdx.x, w = t >> 6, lane = t & 63;
    const int c16 = lane & 15, qd = lane >> 4;
    const int bx = blockIdx.x;
    const int bh = bx >> 5;
    const int l0 = (bx & 31) * Lq;
    const size_t rowbase = (size_t)bh * Nq + l0;
    const float* kb = kin + rowbase * 64;

    /* ---- proj_k via MFMA, h from the same loads ---- */
    f32x4 acc[8];
    float ssum = 0.f;
    #pragma unroll
    for (int nt = 0; nt < 8; ++nt) acc[nt] = (f32x4){0.f, 0.f, 0.f, 0.f};
    #pragma unroll
    for (int kt = 0; kt < 2; ++kt) {
        bf16x8 a = gfrag_h(kb + (size_t)(16 * w + c16) * 64 + kt * 32 + qd * 8, &ssum);
        #pragma unroll
        for (int nt = 0; nt < 8; ++nt) {
            bf16x8 b = *(const bf16x8*)&omb[(size_t)(16 * nt + c16) * 64 + kt * 32 + qd * 8];
            acc[nt] = mfma16(a, b, acc[nt]);
        }
    }
    ssum += __shfl_xor(ssum, 16);
    ssum += __shfl_xor(ssum, 32);
    const float h_red = 0.5f * ssum;
    const int row0 = 16 * w + 4 * qd;
    float h4[4];
    #pragma unroll
    for (int r = 0; r < 4; ++r) h4[r] = __shfl(h_red, 4 * qd + r);

    /* ---- chunk max ---- */
    float lmax = -1e30f;
    #pragma unroll
    for (int r = 0; r < 4; ++r) {
        #pragma unroll
        for (int nt = 0; nt < 8; ++nt) lmax = fmaxf(lmax, acc[nt][r] - h4[r]);
    }
    #pragma unroll
    for (int o = 1; o <= 32; o <<= 1) lmax = fmaxf(lmax, __shfl_xor(lmax, o));
    if (lane == 0) wred[w] = lmax;
    __syncthreads();                               /* barrier 1: wred */
    float mc = wred[0];
    #pragma unroll
    for (int i = 1; i < 8; ++i) mc = fmaxf(mc, wred[i]);
    if (t == 0) partial[bx] = mc;

    /* ---- phi'_k -> PKt[m][l], packed b64 ---- */
    #pragma unroll
    for (int nt = 0; nt < 8; ++nt) {
        union { s16x4 v; unsigned short s[4]; } u;
        #pragma unroll
        for (int r = 0; r < 4; ++r) {
            float pk = __expf(acc[nt][r] - h4[r] - mc) * INVSQRT_M;
            u.s[r] = f2bf(pk);
        }
        *(s16x4*)&PKt[(16 * nt + c16) * KSTR + row0] = u.v;
    }
    __syncthreads();                               /* barrier 2: PKt ready */

    /* ---- S~^T = vT . PK' (wave w owns m-tile w; 4 d-tiles + z) ---- */
    const unsigned short* vTb = vT + (size_t)bh * 64 * Nq + l0;
    f32x4 accS[4], accz;
    #pragma unroll
    for (int dt = 0; dt < 4; ++dt) accS[dt] = (f32x4){0.f, 0.f, 0.f, 0.f};
    accz = (f32x4){0.f, 0.f, 0.f, 0.f};
    const bf16x8 ones = ones_frag();
    #pragma unroll
    for (int kt = 0; kt < 4; ++kt) {
        bf16x8 bfr = *(const bf16x8*)&PKt[(16 * w + c16) * KSTR + kt * 32 + qd * 8];
        #pragma unroll
        for (int dt = 0; dt < 4; ++dt) {
            bf16x8 afr = *(const bf16x8*)&vTb[(size_t)(16 * dt + c16) * Nq + kt * 32 + qd * 8];
            accS[dt] = mfma16(afr, bfr, accS[dt]);
        }
        accz = mfma16(ones, bfr, accz);
    }
    float* sb = Sbuf + (size_t)bx * STATE_STRIDE;
    #pragma unroll
    for (int dt = 0; dt < 4; ++dt) {
        #pragma unroll
        for (int r = 0; r < 4; ++r)
            sb[(16 * dt + 4 * qd + r) * 128 + 16 * w + c16] = accS[dt][r];
    }
    if (qd == 0) sb[64 * 128 + 16 * w + c16] = accz[0];
}

// ---------------------------------------------------------------------------
__global__ void gmax_kernel(const float* __restrict__ partial, int n, float* __restrict__ gmax) {
    float m = -1e30f;
    for (int i = threadIdx.x; i < n; i += 256) m = fmaxf(m, partial[i]);
    #pragma unroll
    for (int o = 1; o <= 32; o <<= 1) m = fmaxf(m, __shfl_xor(m, o));
    __shared__ float w[4];
    if ((threadIdx.x & 63) == 0) w[threadIdx.x >> 6] = m;
    __syncthreads();
    if (threadIdx.x == 0) gmax[0] = fmaxf(fmaxf(w[0], w[1]), fmaxf(w[2], w[3]));
}

// ---------------------------------------------------------------------------
// prefix: exclusive scan of  e^{m_c-gmax} S~^T + eps-terms over chunks,
// written as bf16 WtG[c][dz][perm(m)] — exactly replay's GEMM2 B layout.
// Reads coalesced ([d][m] row-major), in-register scan (ILP).
// ---------------------------------------------------------------------------
#define PBLK 33   /* ceil(8320/256) slices per (b,h) */
__global__ __launch_bounds__(256) void prefix_kernel(
    const float* __restrict__ Sbuf, unsigned short* __restrict__ WtG,
    const float* __restrict__ csumV,
    const float* __restrict__ partial, const float* __restrict__ gmaxp) {
    const int bh = blockIdx.x / PBLK;
    const int e = (blockIdx.x % PBLK) * 256 + threadIdx.x;
    if (e >= STATE_STRIDE) return;
    const float gm = gmaxp[0];
    const int dz = e >> 7, m = e & 127;
    const int wcol = dz * 128 + PERM(m);
    const size_t base = (size_t)bh * Cq * STATE_STRIDE + e;

    float vals[Cq];
    #pragma unroll
    for (int c = 0; c < Cq; ++c) vals[c] = Sbuf[base + (size_t)c * STATE_STRIDE];

    float running = 0.f;
    #pragma unroll
    for (int c = 0; c < Cq; ++c) {
        const int cx = bh * Cq + c;
        float sc = __expf(partial[cx] - gm);
        float ep = (dz == 64) ? (EPS_PHI * 128.0f)
                              : (EPS_PHI * csumV[(size_t)cx * 64 + dz]);
        WtG[(size_t)cx * STATE_STRIDE + wcol] = f2bf(running);
        running += sc * vals[c] + ep;
    }
}

// ---------------------------------------------------------------------------
// replay: proj (omega bf16 direct, h in-register), phi_q/PQ in registers,
// phi_k -> PK (LDS, the only LDS array: 34.8 KB),
// GEMM1 swapped (A_s^T = PK.PQ^T) kept in registers,
// GEMM2 B-frags direct from global: vT (V part), WtG (S_in/z, perm'd),
// const-ones (den V-part). den row broadcast -> every lane owns den.
// launch_bounds (512,4): no forced spills (R5 lesson).
// ---------------------------------------------------------------------------
__global__ __launch_bounds__(512, 4) void replay_kernel(
    const float* __restrict__ q, const float* __restrict__ kin,
    const unsigned short* __restrict__ omb, const unsigned short* __restrict__ vT,
    const unsigned short* __restrict__ WtG,
    const float* __restrict__ gmaxp, float* __restrict__ out) {
    __shared__ __align__(16) unsigned short PK[128 * KSTR];  /* [l][perm(m)] */
    const int t = threadIdx.x, w = t >> 6, lane = t & 63;
    const int c16 = lane & 15, qd = lane >> 4;
    const int bx = blockIdx.x;
    const int bh = bx >> 5;
    const int l0 = (bx & 31) * Lq;
    const size_t rowbase = (size_t)bh * Nq + l0;
    const float* qb = q + rowbase * 64;
    const float* kb = kin + rowbase * 64;
    const float gmax = gmaxp[0];
    const int row0 = 16 * w + 4 * qd;
    const int arow = 16 * w + c16;

    /* ---- proj_q + proj_k fused; h from the k loads ---- */
    f32x4 accq[8], acck[8];
    float ssum = 0.f;
    #pragma unroll
    for (int nt = 0; nt < 8; ++nt) {
        accq[nt] = (f32x4){0.f, 0.f, 0.f, 0.f};
        acck[nt] = (f32x4){0.f, 0.f, 0.f, 0.f};
    }
    #pragma unroll
    for (int kt = 0; kt < 2; ++kt) {
        bf16x8 aq = gfrag(qb + (size_t)arow * 64 + kt * 32 + qd * 8, SCALE);
        bf16x8 ak = gfrag_h(kb + (size_t)arow * 64 + kt * 32 + qd * 8, &ssum);
        #pragma unroll
        for (int nt = 0; nt < 8; ++nt) {
            bf16x8 b = *(const bf16x8*)&omb[(size_t)(16 * nt + c16) * 64 + kt * 32 + qd * 8];
            accq[nt] = mfma16(aq, b, accq[nt]);
            acck[nt] = mfma16(ak, b, acck[nt]);
        }
    }
    ssum += __shfl_xor(ssum, 16);
    ssum += __shfl_xor(ssum, 32);
    const float h_red = 0.5f * ssum;

    /* ---- phi_q into registers (perm-packed pairs) ---- */
    unsigned pqu[4][4];
    #pragma unroll
    for (int r = 0; r < 4; ++r) {
        float mx = accq[0][r];
        #pragma unroll
        for (int nt = 1; nt < 8; ++nt) mx = fmaxf(mx, accq[nt][r]);
        mx = fmaxf(mx, __shfl_xor(mx, 1));
        mx = fmaxf(mx, __shfl_xor(mx, 2));
        mx = fmaxf(mx, __shfl_xor(mx, 4));
        mx = fmaxf(mx, __shfl_xor(mx, 8));
        #pragma unroll
        for (int i = 0; i < 4; ++i) {
            float lo = __expf(accq[2 * i][r]     - mx) * INVSQRT_M + EPS_PHI;
            float hi = __expf(accq[2 * i + 1][r] - mx) * INVSQRT_M + EPS_PHI;
            pqu[r][i] = (unsigned)f2bf(lo) | ((unsigned)f2bf(hi) << 16);
        }
    }
    /* ---- build bq[kt] (PQ A/B-frag for row arow) via shuffles ---- */
    bf16x8 bq[4];
    {
        const int rsel = c16 & 3;
        #pragma unroll
        for (int kt = 0; kt < 4; ++kt) {
            const int src = 4 * kt + qd + ((c16 >> 2) << 4);
            union { bf16x8 v; unsigned u[4]; } tt;
            #pragma unroll
            for (int i = 0; i < 4; ++i) {
                unsigned v0 = __shfl(pqu[0][i], src);
                unsigned v1 = __shfl(pqu[1][i], src);
                unsigned v2 = __shfl(pqu[2][i], src);
                unsigned v3 = __shfl(pqu[3][i], src);
                unsigned s01 = (rsel & 1) ? v1 : v0;
                unsigned s23 = (rsel & 1) ? v3 : v2;
                tt.u[i] = (rsel & 2) ? s23 : s01;
            }
            bq[kt] = tt.v;
        }
    }
    /* ---- phi_k -> PK[l][perm(m)], b128 packed ---- */
    #pragma unroll
    for (int r = 0; r < 4; ++r) {
        float h = __shfl(h_red, 4 * qd + r);
        union { bf16x8 v; unsigned short s[8]; } u;
        #pragma unroll
        for (int nt = 0; nt < 8; ++nt)
            u.s[nt] = f2bf(__expf(acck[nt][r] - h - gmax) * INVSQRT_M + EPS_PHI);
        *(bf16x8*)&PK[(row0 + r) * KSTR + c16 * 8] = u.v;
    }
    __syncthreads();   /* the ONE barrier: PK visibility */

    /* ---- GEMM1 swapped: a1[lt] = D[l][q-tile] ---- */
    f32x4 a1[8];
    #pragma unroll
    for (int lt = 0; lt < 8; ++lt) {
        a1[lt] = (f32x4){0.f, 0.f, 0.f, 0.f};
        #pragma unroll
        for (int kt = 0; kt < 4; ++kt) {
            bf16x8 a = *(const bf16x8*)&PK[(16 * lt + c16) * KSTR + kt * 32 + qd * 8];
            a1[lt] = mfma16(a, bq[kt], a1[lt]);
        }
    }
    /* ---- causal mask + pack A_s to registers ---- */
    unsigned asu[8][2];
    #pragma unroll
    for (int lt = 0; lt < 8; ++lt) {
        const int lbase = 16 * lt + 4 * qd;
        float m0 = (lbase + 0 <= arow) ? a1[lt][0] : 0.f;
        float m1 = (lbase + 1 <= arow) ? a1[lt][1] : 0.f;
        float m2 = (lbase + 2 <= arow) ? a1[lt][2] : 0.f;
        float m3 = (lbase + 3 <= arow) ? a1[lt][3] : 0.f;
        asu[lt][0] = (unsigned)f2bf(m0) | ((unsigned)f2bf(m1) << 16);
        asu[lt][1] = (unsigned)f2bf(m2) | ((unsigned)f2bf(m3) << 16);
    }
    /* ---- GEMM2: [num|den] = [A_s|PQ] . W ---- */
    const unsigned short* vTb = vT + (size_t)bh * 64 * Nq + l0;
    const unsigned short* wg  = WtG + (size_t)bx * STATE_STRIDE;
    const bf16x8 ones = ones_frag();
    f32x4 acc2[5];
    #pragma unroll
    for (int nt = 0; nt < 5; ++nt) acc2[nt] = (f32x4){0.f, 0.f, 0.f, 0.f};
    {
        const int src0 = c16 + ((2 * qd) & 3) * 16;
        const int src1 = c16 + ((2 * qd + 1) & 3) * 16;
        const int hsel = qd >> 1;
        #pragma unroll
        for (int kt = 0; kt < 4; ++kt) {   /* k = l (V half) */
            union { bf16x8 v; unsigned u[4]; } af;
            unsigned a00 = __shfl(asu[2 * kt][0], src0), a10 = __shfl(asu[2 * kt + 1][0], src0);
            unsigned a01 = __shfl(asu[2 * kt][1], src0), a11 = __shfl(asu[2 * kt + 1][1], src0);
            af.u[0] = hsel ? a10 : a00;
            af.u[1] = hsel ? a11 : a01;
            unsigned b00 = __shfl(asu[2 * kt][0], src1), b10 = __shfl(asu[2 * kt + 1][0], src1);
            unsigned b01 = __shfl(asu[2 * kt][1], src1), b11 = __shfl(asu[2 * kt + 1][1], src1);
            af.u[2] = hsel ? b10 : b00;
            af.u[3] = hsel ? b11 : b01;
            #pragma unroll
            for (int nt = 0; nt < 4; ++nt) {
                bf16x8 b = *(const bf16x8*)&vTb[(size_t)(16 * nt + c16) * Nq + kt * 32 + qd * 8];
                acc2[nt] = mfma16(af.v, b, acc2[nt]);
            }
            acc2[4] = mfma16(af.v, ones, acc2[4]);       /* den V-part */
        }
        #pragma unroll
        for (int kt = 0; kt < 4; ++kt) {   /* k = perm(m) (S_in half) */
            #pragma unroll
            for (int nt = 0; nt < 4; ++nt) {
                bf16x8 b = *(const bf16x8*)&wg[(16 * nt + c16) * 128 + kt * 32 + qd * 8];
                acc2[nt] = mfma16(bq[kt], b, acc2[nt]);
            }
            /* den z-part: broadcast row 64 to all cols -> every lane owns den */
            bf16x8 bz = *(const bf16x8*)&wg[64 * 128 + kt * 32 + qd * 8];
            acc2[4] = mfma16(bq[kt], bz, acc2[4]);
        }
    }
    /* ---- epilogue: den is lane-local now ---- */
    #pragma unroll
    for (int r = 0; r < 4; ++r) {
        float den = acc2[4][r] + EPS_DEN;
        float rd = 1.0f / den;
        #pragma unroll
        for (int nt = 0; nt < 4; ++nt)
            out[(rowbase + row0 + r) * 64 + 16 * nt + c16] = acc2[nt][r] * rd;
    }
}

// ---------------------------------------------------------------------------
extern "C" void kernel_launch(void* const* d_in, const int* in_sizes, int n_in,
                              void* d_out, int out_size, void* d_ws, size_t ws_size,
                              hipStream_t stream) {
    const float* q     = (const float*)d_in[0];
    const float* k     = (const float*)d_in[1];
    const float* v     = (const float*)d_in[2];
    const float* omega = (const float*)d_in[3];
    float* out = (float*)d_out;
    float* ws  = (float*)d_ws;

    const int nChunks = Bq * Hq * Cq;            /* 2048 */
    float* partial = ws;                                       /* 2048 */
    float* gmax    = partial + nChunks;                        /* 16 */
    float* csumV   = gmax + 16;                                /* 2048*64 */
    unsigned short* omb = (unsigned short*)(csumV + (size_t)nChunks * 64);      /* 8192 h */
    unsigned short* vT  = omb + 8192;                          /* 64*64*4096 h = 32 MB */
    unsigned short* WtG = vT + (size_t)64 * 64 * Nq;           /* 2048*8320 h = 34 MB */
    float* Sbuf = (float*)(WtG + (size_t)nChunks * STATE_STRIDE);  /* 68 MB f32 */

    vconv_kernel<<<nChunks, 256, 0, stream>>>(v, vT, csumV);
    oconv_kernel<<<1, 256, 0, stream>>>(omega, omb);
    chunkstate_kernel<<<nChunks, 512, 0, stream>>>(k, omb, vT, partial, Sbuf);
    gmax_kernel<<<1, 256, 0, stream>>>(partial, nChunks, gmax);
    prefix_kernel<<<64 * PBLK, 256, 0, stream>>>(Sbuf, WtG, csumV, partial, gmax);
    replay_kernel<<<nChunks, 512, 0, stream>>>(q, k, omb, vT, WtG, gmax, out);
}

// Round 7
// 350.317 us; speedup vs baseline: 1.5266x; 1.1893x over previous
//
#include <hip/hip_runtime.h>
#include <math.h>

#define Bq 4
#define Hq 16
#define Nq 4096
#define Dq 64
#define Mq 128
#define Cq 32                          /* chunks per (b,h); L = 128 */
#define Lq 128
#define EPS_PHI 1e-4f
#define EPS_DEN 1e-6f
#define SCALE 0.35355339059327373f     /* 64^-0.25 */
#define INVSQRT_M 0.08838834764831845f /* 1/sqrt(128) */
#define STATE_STRIDE 8320              /* 65*128: [d|z][m] (f32 Sbuf) */
#define VTF_STRIDE 8192                /* 16 frags * 64 lanes * 8 */
#define WGF_STRIDE 8320                /* 16 frags * 512 + 128 z */

#define KSTR 136   /* PK / PKt row stride, bf16 (128+8) */

/* m-axis permutation: perm(m) = (m&15)*8 + (m>>4). Applied to PQ (regs),
   PK (LDS), and W's m k-space, so all m-contractions are just reordered. */
#define PERM(m) (((m) & 15) * 8 + ((m) >> 4))

typedef __attribute__((ext_vector_type(8))) short bf16x8;
typedef __attribute__((ext_vector_type(4))) short s16x4;
typedef __attribute__((ext_vector_type(4))) float f32x4;

static __device__ inline f32x4 mfma16(bf16x8 a, bf16x8 b, f32x4 c) {
    return __builtin_amdgcn_mfma_f32_16x16x32_bf16(a, b, c, 0, 0, 0);
}

static __device__ inline unsigned short f2bf(float f) {
    unsigned u = __builtin_bit_cast(unsigned, f);
    u += 0x7FFF + ((u >> 16) & 1);          /* RNE */
    return (unsigned short)(u >> 16);
}

static __device__ inline bf16x8 gfrag(const float* p, float scale) {
    float4 a = *(const float4*)p;
    float4 b = *(const float4*)(p + 4);
    union { bf16x8 v; unsigned short s[8]; } u;
    u.s[0] = f2bf(a.x * scale); u.s[1] = f2bf(a.y * scale);
    u.s[2] = f2bf(a.z * scale); u.s[3] = f2bf(a.w * scale);
    u.s[4] = f2bf(b.x * scale); u.s[5] = f2bf(b.y * scale);
    u.s[6] = f2bf(b.z * scale); u.s[7] = f2bf(b.w * scale);
    return u.v;
}

/* K fragment loader that also accumulates sum of squares of scaled values. */
static __device__ inline bf16x8 gfrag_h(const float* p, float* hs) {
    float4 a = *(const float4*)p;
    float4 b = *(const float4*)(p + 4);
    float x0 = a.x * SCALE, x1 = a.y * SCALE, x2 = a.z * SCALE, x3 = a.w * SCALE;
    float x4 = b.x * SCALE, x5 = b.y * SCALE, x6 = b.z * SCALE, x7 = b.w * SCALE;
    *hs += x0 * x0 + x1 * x1 + x2 * x2 + x3 * x3
         + x4 * x4 + x5 * x5 + x6 * x6 + x7 * x7;
    union { bf16x8 v; unsigned short s[8]; } u;
    u.s[0] = f2bf(x0); u.s[1] = f2bf(x1); u.s[2] = f2bf(x2); u.s[3] = f2bf(x3);
    u.s[4] = f2bf(x4); u.s[5] = f2bf(x5); u.s[6] = f2bf(x6); u.s[7] = f2bf(x7);
    return u.v;
}

static __device__ inline bf16x8 ones_frag() {
    union { bf16x8 v; unsigned short s[8]; } u;
    #pragma unroll
    for (int i = 0; i < 8; ++i) u.s[i] = 0x3F80;
    return u.v;
}

// ---------------------------------------------------------------------------
// vconv: per chunk: vTf in FRAGMENT-MAJOR layout
//   vTf[bx][f=kt*4+dt][lane][j] = V[l=kt*32+(lane>>4)*8+j][d=16*dt+(lane&15)]
// so both chunkstate's A-frags and replay's B-frags are base+lane*16B loads.
// Plus csumV (f32 column sums, exact eps term).
// ---------------------------------------------------------------------------
__global__ __launch_bounds__(256) void vconv_kernel(
    const float* __restrict__ vin, unsigned short* __restrict__ vTf,
    float* __restrict__ csumV) {
    __shared__ __align__(16) unsigned short vt_lds[64 * KSTR];
    __shared__ float csum[4][64];
    const int t = threadIdx.x;
    const int bx = blockIdx.x;
    const int bh = bx >> 5;
    const int l0 = (bx & 31) * Lq;
    const float* vb = vin + ((size_t)bh * Nq + l0) * 64;
    const int d = t & 63, g = t >> 6;

    float s = 0.f;
    #pragma unroll
    for (int rep = 0; rep < 32; ++rep) {
        int l = rep * 4 + g;
        float x = vb[(size_t)l * 64 + d];
        s += x;
        vt_lds[d * KSTR + l] = f2bf(x);
    }
    csum[g][d] = s;
    __syncthreads();
    if (t < 64)
        csumV[(size_t)bx * 64 + t] = csum[0][t] + csum[1][t] + csum[2][t] + csum[3][t];
    unsigned short* dst = vTf + (size_t)bx * VTF_STRIDE;
    #pragma unroll
    for (int rep = 0; rep < 4; ++rep) {
        int idx = rep * 256 + t;          /* 1024 b128 segments: f*64+lane */
        int f = idx >> 6, lane = idx & 63;
        int dt = f & 3, kt = f >> 2, c = lane & 15, qq = lane >> 4;
        *(bf16x8*)&dst[(size_t)idx * 8] =
            *(const bf16x8*)&vt_lds[(16 * dt + c) * KSTR + kt * 32 + qq * 8];
    }
}

// ---------------------------------------------------------------------------
// oconv: omega bf16 in FRAGMENT-MAJOR layout
//   ombF[f=kt*8+nt][lane][j] = omega[m=16*nt+(lane&15)][d=kt*32+(lane>>4)*8+j]
// ---------------------------------------------------------------------------
__global__ __launch_bounds__(256) void oconv_kernel(
    const float* __restrict__ omega, unsigned short* __restrict__ ombF) {
    const int t = threadIdx.x;
    #pragma unroll
    for (int rep = 0; rep < 4; ++rep) {
        int g8 = rep * 256 + t;           /* 1024 groups: m = g8>>3, d0 = (g8&7)*8 */
        int m = g8 >> 3, d0 = (g8 & 7) * 8;
        const float* p = omega + (size_t)m * 64 + d0;
        float4 a = *(const float4*)p;
        float4 b = *(const float4*)(p + 4);
        union { bf16x8 v; unsigned short s[8]; } u;
        u.s[0] = f2bf(a.x); u.s[1] = f2bf(a.y); u.s[2] = f2bf(a.z); u.s[3] = f2bf(a.w);
        u.s[4] = f2bf(b.x); u.s[5] = f2bf(b.y); u.s[6] = f2bf(b.z); u.s[7] = f2bf(b.w);
        int kt = d0 >> 5, qq = (d0 >> 3) & 3, nt = m >> 4, c = m & 15;
        *(bf16x8*)&ombF[((size_t)(kt * 8 + nt) * 64 + qq * 16 + c) * 8] = u.v;
    }
}

// ---------------------------------------------------------------------------
// chunkstate: proj_k (h folded into loads, ombF frag-major), chunk max m_c,
// phi' = exp(proj-h-m_c)/sqrt(M) -> PKt[m][l] (LDS), then swapped MFMA:
// S~^T[d][m] = sum_l V^T[d][l] phi'[l][m]  (A-frags coalesced from vTf),
// z~[m] via all-ones A-frag. Output Sbuf = [d(64)|z][m] f32, coalesced.
// launch_bounds (512,4): 128-VGPR budget, no forced spills (R5 lesson).
// ---------------------------------------------------------------------------
__global__ __launch_bounds__(512, 4) void chunkstate_kernel(
    const float* __restrict__ kin, const unsigned short* __restrict__ ombF,
    const unsigned short* __restrict__ vTf,
    float* __restrict__ partial, float* __restrict__ Sbuf) {
    __shared__ __align__(16) unsigned short PKt[128 * KSTR]; /* [m][l] */
    __shared__ float wred[8];
    const int t = threadIdx.x, w = t >> 6, lane = t & 63;
    const int c16 = lane & 15, qd = lane >> 4;
    const int bx = blockIdx.x;
    const int bh = bx >> 5;
    const int l0 = (bx & 31) * Lq;
    const size_t rowbase = (size_t)bh * Nq + l0;
    const float* kb = kin + rowbase * 64;

    /* ---- proj_k via MFMA, h from the same loads ---- */
    f32x4 acc[8];
    float ssum = 0.f;
    #pragma unroll
    for (int nt = 0; nt < 8; ++nt) acc[nt] = (f32x4){0.f, 0.f, 0.f, 0.f};
    #pragma unroll
    for (int kt = 0; kt < 2; ++kt) {
        bf16x8 a = gfrag_h(kb + (size_t)(16 * w + c16) * 64 + kt * 32 + qd * 8, &ssum);
        #pragma unroll
        for (int nt = 0; nt < 8; ++nt) {
            bf16x8 b = *(const bf16x8*)&ombF[((size_t)(kt * 8 + nt) * 64 + lane) * 8];
            acc[nt] = mfma16(a, b, acc[nt]);
        }
    }
    ssum += __shfl_xor(ssum, 16);
    ssum += __shfl_xor(ssum, 32);
    const float h_red = 0.5f * ssum;
    const int row0 = 16 * w + 4 * qd;
    float h4[4];
    #pragma unroll
    for (int r = 0; r < 4; ++r) h4[r] = __shfl(h_red, 4 * qd + r);

    /* ---- chunk max ---- */
    float lmax = -1e30f;
    #pragma unroll
    for (int r = 0; r < 4; ++r) {
        #pragma unroll
        for (int nt = 0; nt < 8; ++nt) lmax = fmaxf(lmax, acc[nt][r] - h4[r]);
    }
    #pragma unroll
    for (int o = 1; o <= 32; o <<= 1) lmax = fmaxf(lmax, __shfl_xor(lmax, o));
    if (lane == 0) wred[w] = lmax;
    __syncthreads();                               /* barrier 1: wred */
    float mc = wred[0];
    #pragma unroll
    for (int i = 1; i < 8; ++i) mc = fmaxf(mc, wred[i]);
    if (t == 0) partial[bx] = mc;

    /* ---- phi'_k -> PKt[m][l], packed b64 ---- */
    #pragma unroll
    for (int nt = 0; nt < 8; ++nt) {
        union { s16x4 v; unsigned short s[4]; } u;
        #pragma unroll
        for (int r = 0; r < 4; ++r) {
            float pk = __expf(acc[nt][r] - h4[r] - mc) * INVSQRT_M;
            u.s[r] = f2bf(pk);
        }
        *(s16x4*)&PKt[(16 * nt + c16) * KSTR + row0] = u.v;
    }
    __syncthreads();                               /* barrier 2: PKt ready */

    /* ---- S~^T = V^T . PK' (wave w owns m-tile w; 4 d-tiles + z) ---- */
    const unsigned short* vf = vTf + (size_t)bx * VTF_STRIDE;
    f32x4 accS[4], accz;
    #pragma unroll
    for (int dt = 0; dt < 4; ++dt) accS[dt] = (f32x4){0.f, 0.f, 0.f, 0.f};
    accz = (f32x4){0.f, 0.f, 0.f, 0.f};
    const bf16x8 ones = ones_frag();
    #pragma unroll
    for (int kt = 0; kt < 4; ++kt) {
        bf16x8 bfr = *(const bf16x8*)&PKt[(16 * w + c16) * KSTR + kt * 32 + qd * 8];
        #pragma unroll
        for (int dt = 0; dt < 4; ++dt) {
            bf16x8 afr = *(const bf16x8*)&vf[((size_t)(kt * 4 + dt) * 64 + lane) * 8];
            accS[dt] = mfma16(afr, bfr, accS[dt]);
        }
        accz = mfma16(ones, bfr, accz);
    }
    float* sb = Sbuf + (size_t)bx * STATE_STRIDE;
    #pragma unroll
    for (int dt = 0; dt < 4; ++dt) {
        #pragma unroll
        for (int r = 0; r < 4; ++r)
            sb[(16 * dt + 4 * qd + r) * 128 + 16 * w + c16] = accS[dt][r];
    }
    if (qd == 0) sb[64 * 128 + 16 * w + c16] = accz[0];
}

// ---------------------------------------------------------------------------
__global__ void gmax_kernel(const float* __restrict__ partial, int n, float* __restrict__ gmax) {
    float m = -1e30f;
    for (int i = threadIdx.x; i < n; i += 256) m = fmaxf(m, partial[i]);
    #pragma unroll
    for (int o = 1; o <= 32; o <<= 1) m = fmaxf(m, __shfl_xor(m, o));
    __shared__ float w[4];
    if ((threadIdx.x & 63) == 0) w[threadIdx.x >> 6] = m;
    __syncthreads();
    if (threadIdx.x == 0) gmax[0] = fmaxf(fmaxf(w[0], w[1]), fmaxf(w[2], w[3]));
}

// ---------------------------------------------------------------------------
// prefix: exclusive scan of  e^{m_c-gmax} S~^T + eps-terms over chunks,
// written bf16 in FRAGMENT-MAJOR layout:
//   wgF[cx][f=kt*4+nt][lane][j] = W[d=16nt+(lane&15)][pm=kt*32+(lane>>4)*8+j]
//   wgF[cx][8192 + pm]          = z_in[m],  pm = PERM(m)
// Reads coalesced ([d|z][m] f32 row-major), in-register scan (ILP).
// ---------------------------------------------------------------------------
#define PBLK 33   /* ceil(8320/256) slices per (b,h) */
__global__ __launch_bounds__(256) void prefix_kernel(
    const float* __restrict__ Sbuf, unsigned short* __restrict__ wgF,
    const float* __restrict__ csumV,
    const float* __restrict__ partial, const float* __restrict__ gmaxp) {
    const int bh = blockIdx.x / PBLK;
    const int e = (blockIdx.x % PBLK) * 256 + threadIdx.x;
    if (e >= STATE_STRIDE) return;
    const float gm = gmaxp[0];
    const int dz = e >> 7, m = e & 127;
    const int pm = PERM(m);
    size_t widx;
    if (dz == 64) {
        widx = 8192 + pm;
    } else {
        const int f    = (pm >> 5) * 4 + (dz >> 4);
        const int lane = ((pm >> 3) & 3) * 16 + (dz & 15);
        widx = (size_t)f * 512 + lane * 8 + (pm & 7);
    }
    const size_t base = (size_t)bh * Cq * STATE_STRIDE + e;

    float vals[Cq];
    #pragma unroll
    for (int c = 0; c < Cq; ++c) vals[c] = Sbuf[base + (size_t)c * STATE_STRIDE];

    float running = 0.f;
    #pragma unroll
    for (int c = 0; c < Cq; ++c) {
        const int cx = bh * Cq + c;
        float sc = __expf(partial[cx] - gm);
        float ep = (dz == 64) ? (EPS_PHI * 128.0f)
                              : (EPS_PHI * csumV[(size_t)cx * 64 + dz]);
        wgF[(size_t)cx * WGF_STRIDE + widx] = f2bf(running);
        running += sc * vals[c] + ep;
    }
}

// ---------------------------------------------------------------------------
// replay: proj (ombF frag-major, h in-register), phi_q/PQ in registers,
// phi_k -> PK (LDS, the only LDS array: 34.8 KB),
// GEMM1 swapped (A_s^T = PK.PQ^T) kept in registers,
// GEMM2 B-frags COALESCED from global frag-major vTf (V half) and wgF
// (S_in half); z-row broadcast; const-ones (den V-part); lane-local den.
// ---------------------------------------------------------------------------
__global__ __launch_bounds__(512, 4) void replay_kernel(
    const float* __restrict__ q, const float* __restrict__ kin,
    const unsigned short* __restrict__ ombF, const unsigned short* __restrict__ vTf,
    const unsigned short* __restrict__ wgF,
    const float* __restrict__ gmaxp, float* __restrict__ out) {
    __shared__ __align__(16) unsigned short PK[128 * KSTR];  /* [l][perm(m)] */
    const int t = threadIdx.x, w = t >> 6, lane = t & 63;
    const int c16 = lane & 15, qd = lane >> 4;
    const int bx = blockIdx.x;
    const int bh = bx >> 5;
    const int l0 = (bx & 31) * Lq;
    const size_t rowbase = (size_t)bh * Nq + l0;
    const float* qb = q + rowbase * 64;
    const float* kb = kin + rowbase * 64;
    const float gmax = gmaxp[0];
    const int row0 = 16 * w + 4 * qd;
    const int arow = 16 * w + c16;

    /* ---- proj_q + proj_k fused; h from the k loads ---- */
    f32x4 accq[8], acck[8];
    float ssum = 0.f;
    #pragma unroll
    for (int nt = 0; nt < 8; ++nt) {
        accq[nt] = (f32x4){0.f, 0.f, 0.f, 0.f};
        acck[nt] = (f32x4){0.f, 0.f, 0.f, 0.f};
    }
    #pragma unroll
    for (int kt = 0; kt < 2; ++kt) {
        bf16x8 aq = gfrag(qb + (size_t)arow * 64 + kt * 32 + qd * 8, SCALE);
        bf16x8 ak = gfrag_h(kb + (size_t)arow * 64 + kt * 32 + qd * 8, &ssum);
        #pragma unroll
        for (int nt = 0; nt < 8; ++nt) {
            bf16x8 b = *(const bf16x8*)&ombF[((size_t)(kt * 8 + nt) * 64 + lane) * 8];
            accq[nt] = mfma16(aq, b, accq[nt]);
            acck[nt] = mfma16(ak, b, acck[nt]);
        }
    }
    ssum += __shfl_xor(ssum, 16);
    ssum += __shfl_xor(ssum, 32);
    const float h_red = 0.5f * ssum;

    /* ---- phi_q into registers (perm-packed pairs) ---- */
    unsigned pqu[4][4];
    #pragma unroll
    for (int r = 0; r < 4; ++r) {
        float mx = accq[0][r];
        #pragma unroll
        for (int nt = 1; nt < 8; ++nt) mx = fmaxf(mx, accq[nt][r]);
        mx = fmaxf(mx, __shfl_xor(mx, 1));
        mx = fmaxf(mx, __shfl_xor(mx, 2));
        mx = fmaxf(mx, __shfl_xor(mx, 4));
        mx = fmaxf(mx, __shfl_xor(mx, 8));
        #pragma unroll
        for (int i = 0; i < 4; ++i) {
            float lo = __expf(accq[2 * i][r]     - mx) * INVSQRT_M + EPS_PHI;
            float hi = __expf(accq[2 * i + 1][r] - mx) * INVSQRT_M + EPS_PHI;
            pqu[r][i] = (unsigned)f2bf(lo) | ((unsigned)f2bf(hi) << 16);
        }
    }
    /* ---- build bq[kt] (PQ A/B-frag for row arow) via shuffles ---- */
    bf16x8 bq[4];
    {
        const int rsel = c16 & 3;
        #pragma unroll
        for (int kt = 0; kt < 4; ++kt) {
            const int src = 4 * kt + qd + ((c16 >> 2) << 4);
            union { bf16x8 v; unsigned u[4]; } tt;
            #pragma unroll
            for (int i = 0; i < 4; ++i) {
                unsigned v0 = __shfl(pqu[0][i], src);
                unsigned v1 = __shfl(pqu[1][i], src);
                unsigned v2 = __shfl(pqu[2][i], src);
                unsigned v3 = __shfl(pqu[3][i], src);
                unsigned s01 = (rsel & 1) ? v1 : v0;
                unsigned s23 = (rsel & 1) ? v3 : v2;
                tt.u[i] = (rsel & 2) ? s23 : s01;
            }
            bq[kt] = tt.v;
        }
    }
    /* ---- phi_k -> PK[l][perm(m)], b128 packed ---- */
    #pragma unroll
    for (int r = 0; r < 4; ++r) {
        float h = __shfl(h_red, 4 * qd + r);
        union { bf16x8 v; unsigned short s[8]; } u;
        #pragma unroll
        for (int nt = 0; nt < 8; ++nt)
            u.s[nt] = f2bf(__expf(acck[nt][r] - h - gmax) * INVSQRT_M + EPS_PHI);
        *(bf16x8*)&PK[(row0 + r) * KSTR + c16 * 8] = u.v;
    }
    __syncthreads();   /* the ONE barrier: PK visibility */

    /* ---- GEMM1 swapped: a1[lt] = D[l][q-tile] ---- */
    f32x4 a1[8];
    #pragma unroll
    for (int lt = 0; lt < 8; ++lt) {
        a1[lt] = (f32x4){0.f, 0.f, 0.f, 0.f};
        #pragma unroll
        for (int kt = 0; kt < 4; ++kt) {
            bf16x8 a = *(const bf16x8*)&PK[(16 * lt + c16) * KSTR + kt * 32 + qd * 8];
            a1[lt] = mfma16(a, bq[kt], a1[lt]);
        }
    }
    /* ---- causal mask + pack A_s to registers ---- */
    unsigned asu[8][2];
    #pragma unroll
    for (int lt = 0; lt < 8; ++lt) {
        const int lbase = 16 * lt + 4 * qd;
        float m0 = (lbase + 0 <= arow) ? a1[lt][0] : 0.f;
        float m1 = (lbase + 1 <= arow) ? a1[lt][1] : 0.f;
        float m2 = (lbase + 2 <= arow) ? a1[lt][2] : 0.f;
        float m3 = (lbase + 3 <= arow) ? a1[lt][3] : 0.f;
        asu[lt][0] = (unsigned)f2bf(m0) | ((unsigned)f2bf(m1) << 16);
        asu[lt][1] = (unsigned)f2bf(m2) | ((unsigned)f2bf(m3) << 16);
    }
    /* ---- GEMM2: [num|den] = [A_s|PQ] . W ---- */
    const unsigned short* vf = vTf + (size_t)bx * VTF_STRIDE;
    const unsigned short* wg = wgF + (size_t)bx * WGF_STRIDE;
    const bf16x8 ones = ones_frag();
    f32x4 acc2[5];
    #pragma unroll
    for (int nt = 0; nt < 5; ++nt) acc2[nt] = (f32x4){0.f, 0.f, 0.f, 0.f};
    {
        const int src0 = c16 + ((2 * qd) & 3) * 16;
        const int src1 = c16 + ((2 * qd + 1) & 3) * 16;
        const int hsel = qd >> 1;
        #pragma unroll
        for (int kt = 0; kt < 4; ++kt) {   /* k = l (V half) */
            union { bf16x8 v; unsigned u[4]; } af;
            unsigned a00 = __shfl(asu[2 * kt][0], src0), a10 = __shfl(asu[2 * kt + 1][0], src0);
            unsigned a01 = __shfl(asu[2 * kt][1], src0), a11 = __shfl(asu[2 * kt + 1][1], src0);
            af.u[0] = hsel ? a10 : a00;
            af.u[1] = hsel ? a11 : a01;
            unsigned b00 = __shfl(asu[2 * kt][0], src1), b10 = __shfl(asu[2 * kt + 1][0], src1);
            unsigned b01 = __shfl(asu[2 * kt][1], src1), b11 = __shfl(asu[2 * kt + 1][1], src1);
            af.u[2] = hsel ? b10 : b00;
            af.u[3] = hsel ? b11 : b01;
            #pragma unroll
            for (int nt = 0; nt < 4; ++nt) {
                bf16x8 b = *(const bf16x8*)&vf[((size_t)(kt * 4 + nt) * 64 + lane) * 8];
                acc2[nt] = mfma16(af.v, b, acc2[nt]);
            }
            acc2[4] = mfma16(af.v, ones, acc2[4]);       /* den V-part */
        }
        #pragma unroll
        for (int kt = 0; kt < 4; ++kt) {   /* k = perm(m) (S_in half) */
            #pragma unroll
            for (int nt = 0; nt < 4; ++nt) {
                bf16x8 b = *(const bf16x8*)&wg[((size_t)(kt * 4 + nt) * 64 + lane) * 8];
                acc2[nt] = mfma16(bq[kt], b, acc2[nt]);
            }
            /* den z-part: broadcast z row to all cols -> every lane owns den */
            bf16x8 bz = *(const bf16x8*)&wg[8192 + kt * 32 + qd * 8];
            acc2[4] = mfma16(bq[kt], bz, acc2[4]);
        }
    }
    /* ---- epilogue: den is lane-local ---- */
    #pragma unroll
    for (int r = 0; r < 4; ++r) {
        float den = acc2[4][r] + EPS_DEN;
        float rd = 1.0f / den;
        #pragma unroll
        for (int nt = 0; nt < 4; ++nt)
            out[(rowbase + row0 + r) * 64 + 16 * nt + c16] = acc2[nt][r] * rd;
    }
}

// ---------------------------------------------------------------------------
extern "C" void kernel_launch(void* const* d_in, const int* in_sizes, int n_in,
                              void* d_out, int out_size, void* d_ws, size_t ws_size,
                              hipStream_t stream) {
    const float* q     = (const float*)d_in[0];
    const float* k     = (const float*)d_in[1];
    const float* v     = (const float*)d_in[2];
    const float* omega = (const float*)d_in[3];
    float* out = (float*)d_out;
    float* ws  = (float*)d_ws;

    const int nChunks = Bq * Hq * Cq;            /* 2048 */
    float* partial = ws;                                       /* 2048 */
    float* gmax    = partial + nChunks;                        /* 16 */
    float* csumV   = gmax + 16;                                /* 2048*64 */
    unsigned short* ombF = (unsigned short*)(csumV + (size_t)nChunks * 64);   /* 8192 h */
    unsigned short* vTf  = ombF + 8192;                        /* 2048*8192 h = 32 MB */
    unsigned short* wgF  = vTf + (size_t)nChunks * VTF_STRIDE; /* 2048*8320 h = 34 MB */
    float* Sbuf = (float*)(wgF + (size_t)nChunks * WGF_STRIDE);    /* 68 MB f32 */

    vconv_kernel<<<nChunks, 256, 0, stream>>>(v, vTf, csumV);
    oconv_kernel<<<1, 256, 0, stream>>>(omega, ombF);
    chunkstate_kernel<<<nChunks, 512, 0, stream>>>(k, ombF, vTf, partial, Sbuf);
    gmax_kernel<<<1, 256, 0, stream>>>(partial, nChunks, gmax);
    prefix_kernel<<<64 * PBLK, 256, 0, stream>>>(Sbuf, wgF, csumV, partial, gmax);
    replay_kernel<<<nChunks, 512, 0, stream>>>(q, k, ombF, vTf, wgF, gmax, out);
}